// Round 2
// baseline (2512.036 us; speedup 1.0000x reference)
//
#include <hip/hip_runtime.h>
#include <hip/hip_bf16.h>
#include <cmath>

typedef __bf16 bf16;
typedef __attribute__((ext_vector_type(8))) __bf16 bf16x8;
typedef __attribute__((ext_vector_type(4))) __bf16 bf16x4;
typedef __attribute__((ext_vector_type(4))) float f32x4;

#define TEMPC 65.0f
#define EPSC 1e-6f

#define GLD_LDS16(gptr, lptr)                                                             \
    __builtin_amdgcn_global_load_lds(                                                     \
        (const __attribute__((address_space(1))) unsigned int*)(gptr),                    \
        (__attribute__((address_space(3))) unsigned int*)(lptr), 16, 0, 0)

// ---------------- f32 -> bf16 convert ----------------
__global__ void conv_kernel(const float* __restrict__ s, bf16* __restrict__ d, int n)
{
    int i = (blockIdx.x * blockDim.x + threadIdx.x) * 4;
    const int stride = gridDim.x * blockDim.x * 4;
    for (; i < n; i += stride) {
        const float4 v = *(const float4*)(s + i);
        bf16x4 o;
        o[0] = (bf16)v.x; o[1] = (bf16)v.y; o[2] = (bf16)v.z; o[3] = (bf16)v.w;
        *(bf16x4*)(d + i) = o;
    }
}

// ---------------- m97-style MFMA GEMM: gathered-A [128 rows] @ W^T ----------------
// 128x128 C-tile, BK=32, single-buffered LDS, global_load_lds width-16 staging.
// MODE 0: store XW = acc + b_ih (bf16)    MODE 1: 10-sample loop; fused dist epilogue
template<int MODE>
__global__ __launch_bounds__(256)
void gemm_kernel(const int* __restrict__ idx, const bf16* __restrict__ emb,
                 const bf16* __restrict__ Wmat, const float* __restrict__ bih,
                 const bf16* __restrict__ Ust, const bf16* __restrict__ prevb,
                 bf16* __restrict__ XWout, float* __restrict__ dist)
{
    __shared__ __align__(16) bf16 As[128 * 32];   // [row][32 bf16] = 64B rows
    __shared__ __align__(16) bf16 Bs[128 * 32];

    const int tid = threadIdx.x;
    const int l  = tid & 63;
    const int w  = tid >> 6;
    const int wr = w >> 1, wc = w & 1;            // wave quadrant (64x64)
    const int wgid  = (blockIdx.x & 7) * 64 + (blockIdx.x >> 3);  // XCD swizzle
    const int mbase = (wgid >> 3) * 128;
    const int nbase = (wgid & 7) * 128;

    // staging: wave w stages 16B chunks g0=w*128+l and g1=g0+64 (for A and B)
    const int g0 = w * 128 + l;
    const int g1 = g0 + 64;
    const int r0 = g0 >> 2, c0 = (g0 & 3) * 16;   // row, byte-in-slice
    const int r1 = g1 >> 2, c1 = (g1 & 3) * 16;
    bf16* AsD0 = As + w * 1024;                   // byte w*2048; +lane*16 implicit
    bf16* AsD1 = As + w * 1024 + 512;
    bf16* BsD0 = Bs + w * 1024;
    bf16* BsD1 = Bs + w * 1024 + 512;
    const char* Bsrc0 = (const char*)Wmat + (size_t)(nbase + r0) * 2048 + c0;
    const char* Bsrc1 = (const char*)Wmat + (size_t)(nbase + r1) * 2048 + c1;

    // fragment read bases: row=(l&15), k-chunk=(l>>4)*8 bf16
    const int frow = l & 15;
    const int kofs = (l >> 4) * 8;
    const bf16* Ard = As + (wr * 64 + frow) * 32 + kofs;
    const bf16* Brd = Bs + (wc * 64 + frow) * 32 + kofs;

    const int NS = MODE ? 10 : 1;
    for (int s = 0; s < NS; ++s) {
        const char* Asrc0 = (const char*)emb + (size_t)idx[s * 8192 + mbase + r0] * 2048 + c0;
        const char* Asrc1 = (const char*)emb + (size_t)idx[s * 8192 + mbase + r1] * 2048 + c1;

        f32x4 acc[4][4] = {};
        for (int kb = 0; kb < 2048; kb += 64) {   // K-slice byte offset (32 bf16)
            GLD_LDS16(Asrc0 + kb, AsD0);
            GLD_LDS16(Asrc1 + kb, AsD1);
            GLD_LDS16(Bsrc0 + kb, BsD0);
            GLD_LDS16(Bsrc1 + kb, BsD1);
            asm volatile("s_waitcnt vmcnt(0)" ::: "memory");
            __syncthreads();
            bf16x8 af[4], bfr[4];
            #pragma unroll
            for (int mt = 0; mt < 4; ++mt) af[mt]  = *(const bf16x8*)(Ard + mt * 16 * 32);
            #pragma unroll
            for (int nt = 0; nt < 4; ++nt) bfr[nt] = *(const bf16x8*)(Brd + nt * 16 * 32);
            #pragma unroll
            for (int mt = 0; mt < 4; ++mt)
                #pragma unroll
                for (int nt = 0; nt < 4; ++nt)
                    acc[mt][nt] = __builtin_amdgcn_mfma_f32_16x16x32_bf16(af[mt], bfr[nt], acc[mt][nt], 0, 0, 0);
            __syncthreads();
        }

        if (MODE == 0) {
            #pragma unroll
            for (int mt = 0; mt < 4; ++mt)
                #pragma unroll
                for (int nt = 0; nt < 4; ++nt) {
                    const int colg = nbase + wc * 64 + nt * 16 + frow;
                    const float bi = bih[colg];
                    #pragma unroll
                    for (int r = 0; r < 4; ++r) {
                        const int rowg = mbase + wr * 64 + mt * 16 + (l >> 4) * 4 + r;
                        XWout[(size_t)rowg * 1024 + colg] = (bf16)(acc[mt][nt][r] + bi);
                    }
                }
        } else {
            #pragma unroll
            for (int mt = 0; mt < 4; ++mt)
                #pragma unroll
                for (int r = 0; r < 4; ++r) {
                    const int rowg = mbase + wr * 64 + mt * 16 + (l >> 4) * 4 + r;
                    float p = 0.f;
                    #pragma unroll
                    for (int nt = 0; nt < 4; ++nt) {
                        const int colg = nbase + wc * 64 + nt * 16 + frow;
                        const size_t e = (size_t)rowg * 1024 + colg;
                        const float o = tanhf(acc[mt][nt][r] + (float)Ust[e]);
                        const float d = (float)prevb[e] - o + EPSC;
                        p += d * d;
                    }
                    #pragma unroll
                    for (int off = 1; off < 16; off <<= 1)
                        p += __shfl_xor(p, off, 16);
                    if (frow == 0) atomicAdd(&dist[s * 8192 + rowg], p);
                }
        }
    }
}

// ---------------- fused 128-step RNN: persistent, device-wide step barrier ----------------
// 64 wgs x 256 thr; wg owns 16 cols (Whh slice in 128 VGPRs); wave w = batch rows [w*16,w*16+16)
__global__ __launch_bounds__(256, 1)
void rnn_fused(bf16* __restrict__ raw, const bf16* __restrict__ Whh,
               const bf16* __restrict__ XWb, const float* __restrict__ bih,
               const float* __restrict__ bhh, bf16* __restrict__ Ust,
               int* __restrict__ cnt)
{
    const int tid  = threadIdx.x;
    const int l    = tid & 63;
    const int w    = tid >> 6;
    const int frow = l & 15;
    const int kofs = (l >> 4) * 8;
    const int j    = blockIdx.x * 16 + frow;

    bf16x8 Bf[32];                                 // Whh[j][:] fragments, resident all steps
    {
        const bf16* bp = Whh + (size_t)j * 1024 + kofs;
        #pragma unroll
        for (int kk = 0; kk < 32; ++kk) Bf[kk] = *(const bf16x8*)(bp + kk * 32);
    }
    const float bh = bhh[j];
    const float bi = bih[j];

    for (int t = 0; t < 128; ++t) {
        const bf16* Ap = raw + (size_t)t * 65536 + (size_t)(w * 16 + frow) * 1024 + kofs;
        f32x4 acc0 = {0.f,0.f,0.f,0.f}, acc1 = {0.f,0.f,0.f,0.f};
        #pragma unroll 8
        for (int kk = 0; kk < 32; kk += 2) {
            bf16x8 a0 = *(const bf16x8*)(Ap + kk * 32);
            bf16x8 a1 = *(const bf16x8*)(Ap + kk * 32 + 32);
            acc0 = __builtin_amdgcn_mfma_f32_16x16x32_bf16(a0, Bf[kk],     acc0, 0, 0, 0);
            acc1 = __builtin_amdgcn_mfma_f32_16x16x32_bf16(a1, Bf[kk + 1], acc1, 0, 0, 0);
        }
        bf16* rawN = raw + (size_t)(t + 1) * 65536;
        #pragma unroll
        for (int r = 0; r < 4; ++r) {
            const int b = w * 16 + (l >> 4) * 4 + r;
            const float V = acc0[r] + acc1[r] + bh;          // h_t @ W_hh^T + b_hh
            const size_t e = (size_t)(t * 64 + b) * 1024 + j;
            const float h = tanhf((float)XWb[e] + V);        // XWb holds +b_ih
            rawN[(size_t)b * 1024 + j] = (bf16)h;
            Ust[e] = (bf16)(V + bi);                         // hiddens_U + b_ih (phase D)
        }
        if (t < 127) {                                       // device-wide step barrier
            __syncthreads();                                 // all stores vmcnt-drained
            if (tid == 0) {
                __threadfence();                             // wbl2: writes visible cross-XCD
                __hip_atomic_fetch_add(&cnt[t], 1, __ATOMIC_RELEASE, __HIP_MEMORY_SCOPE_AGENT);
                while (__hip_atomic_load(&cnt[t], __ATOMIC_ACQUIRE, __HIP_MEMORY_SCOPE_AGENT) < 64)
                    __builtin_amdgcn_s_sleep(2);
            }
            __syncthreads();
        }
    }
}

// ---------------- pos term: (65/128) * sum (raw[t]-raw[t+1]+eps)^2 ----------------
__global__ void pos_kernel(const bf16* __restrict__ raw, float* __restrict__ lacc)
{
    float s = 0.f;
    const int NV = (128 * 64 * 1024) / 8;
    for (int i = blockIdx.x * blockDim.x + threadIdx.x; i < NV; i += gridDim.x * blockDim.x) {
        bf16x8 a = *(const bf16x8*)(raw + (size_t)i * 8);
        bf16x8 b = *(const bf16x8*)(raw + (size_t)i * 8 + 65536);
        #pragma unroll
        for (int j = 0; j < 8; ++j) {
            const float d = (float)a[j] - (float)b[j] + EPSC;
            s += d * d;
        }
    }
    #pragma unroll
    for (int off = 32; off > 0; off >>= 1) s += __shfl_down(s, off, 64);
    if ((threadIdx.x & 63) == 0) atomicAdd(lacc, s * (TEMPC / 128.f));
}

// ---------------- finalize: clip, exp, log, total ----------------
__global__ __launch_bounds__(1024)
void finalize_kernel(const float* __restrict__ dist, const float* __restrict__ lacc,
                     float* __restrict__ out)
{
    float s = 0.f;
    for (int r = threadIdx.x; r < 8192; r += 1024) {
        float se = 0.f;
        #pragma unroll
        for (int k = 0; k < 10; ++k) {
            float dd = dist[k * 8192 + r];
            dd = fminf(fmaxf(dd, 0.f), 0.01f);
            se += expf(-dd);
        }
        s += logf(se * (1.f / 8192.f) + EPSC);
    }
    #pragma unroll
    for (int off = 32; off > 0; off >>= 1) s += __shfl_down(s, off, 64);
    __shared__ float red[16];
    const int wave = threadIdx.x >> 6;
    if ((threadIdx.x & 63) == 0) red[wave] = s;
    __syncthreads();
    if (threadIdx.x == 0) {
        float tot = 0.f;
        #pragma unroll
        for (int i = 0; i < 16; ++i) tot += red[i];
        out[0] = tot + lacc[0];
    }
}

extern "C" void kernel_launch(void* const* d_in, const int* in_sizes, int n_in,
                              void* d_out, int out_size, void* d_ws, size_t ws_size,
                              hipStream_t stream)
{
    const int*   data    = (const int*)d_in[0];   // [128*64]
    const int*   samples = (const int*)d_in[1];   // [10*8192]
    const float* emb     = (const float*)d_in[2]; // [32000*1024]
    const float* Wih     = (const float*)d_in[3]; // [1024*1024]
    const float* bih     = (const float*)d_in[4]; // [1024]
    const float* Whh     = (const float*)d_in[5]; // [1024*1024]
    const float* bhh     = (const float*)d_in[6]; // [1024]

    char* ws = (char*)d_ws;
    size_t off = 0;
    auto alloc = [&](size_t bytes) { void* p = ws + off; off += (bytes + 255) & ~(size_t)255; return p; };
    bf16*  emb_b = (bf16*)alloc((size_t)32000 * 1024 * 2);
    bf16*  Wih_b = (bf16*)alloc((size_t)1024 * 1024 * 2);
    bf16*  Whh_b = (bf16*)alloc((size_t)1024 * 1024 * 2);
    bf16*  XWb   = (bf16*)alloc((size_t)8192 * 1024 * 2);
    bf16*  Ust   = (bf16*)alloc((size_t)8192 * 1024 * 2);
    bf16*  raw   = (bf16*)alloc((size_t)129 * 64 * 1024 * 2);
    float* dist  = (float*)alloc((size_t)10 * 8192 * 4);
    float* lacc  = (float*)alloc(256);
    int*   cnt   = (int*)alloc(128 * 4);

    hipMemsetAsync(raw,  0, 64 * 1024 * 2, stream);   // h0 = 0 (raw[0])
    hipMemsetAsync(dist, 0, 10 * 8192 * 4, stream);
    hipMemsetAsync(lacc, 0, 256, stream);
    hipMemsetAsync(cnt,  0, 128 * 4, stream);         // step-barrier counters

    conv_kernel<<<2048, 256, 0, stream>>>(emb, emb_b, 32000 * 1024);
    conv_kernel<<<512, 256, 0, stream>>>(Wih, Wih_b, 1024 * 1024);
    conv_kernel<<<512, 256, 0, stream>>>(Whh, Whh_b, 1024 * 1024);

    // Phase A: XWb = emb[data] @ Wih^T + bih  (bf16)
    gemm_kernel<0><<<512, 256, 0, stream>>>(data, emb_b, Wih_b, bih,
                                            nullptr, nullptr, XWb, nullptr);
    // Phase B: all 128 RNN steps in one persistent kernel
    rnn_fused<<<64, 256, 0, stream>>>(raw, Whh_b, XWb, bih, bhh, Ust, cnt);

    // pos term
    pos_kernel<<<512, 256, 0, stream>>>(raw, lacc);

    // Phase D: sampled negatives GEMM + fused dist epilogue
    gemm_kernel<1><<<512, 256, 0, stream>>>(samples, emb_b, Wih_b, bih,
                                            Ust, raw, nullptr, dist);

    finalize_kernel<<<1, 1024, 0, stream>>>(dist, lacc, (float*)d_out);
}

// Round 3
// 2337.526 us; speedup vs baseline: 1.0747x; 1.0747x over previous
//
#include <hip/hip_runtime.h>
#include <hip/hip_bf16.h>
#include <cmath>

typedef __bf16 bf16;
typedef __attribute__((ext_vector_type(8))) __bf16 bf16x8;
typedef __attribute__((ext_vector_type(4))) __bf16 bf16x4;
typedef __attribute__((ext_vector_type(4))) float f32x4;

#define TEMPC 65.0f
#define EPSC 1e-6f

#define GLD_LDS16(gptr, lptr)                                                             \
    __builtin_amdgcn_global_load_lds(                                                     \
        (const __attribute__((address_space(1))) unsigned int*)(gptr),                    \
        (__attribute__((address_space(3))) unsigned int*)(lptr), 16, 0, 0)

// ---------------- f32 -> bf16 convert ----------------
__global__ void conv_kernel(const float* __restrict__ s, bf16* __restrict__ d, int n)
{
    int i = (blockIdx.x * blockDim.x + threadIdx.x) * 4;
    const int stride = gridDim.x * blockDim.x * 4;
    for (; i < n; i += stride) {
        const float4 v = *(const float4*)(s + i);
        bf16x4 o;
        o[0] = (bf16)v.x; o[1] = (bf16)v.y; o[2] = (bf16)v.z; o[3] = (bf16)v.w;
        *(bf16x4*)(d + i) = o;
    }
}

// ---------------- 2-phase pipelined MFMA GEMM: gathered-A [128 rows] @ W^T ----------------
// 128x128 C-tile, BK=32, double-buffered LDS, global_load_lds width-16 staging.
// Stage(next) issued BEFORE MFMA(cur); one vmcnt(0)+barrier per K-step.
// MODE 0: store XW = acc + b_ih (bf16)    MODE 1: 10-sample loop; fused dist epilogue
template<int MODE>
__global__ __launch_bounds__(256)
void gemm_kernel(const int* __restrict__ idx, const bf16* __restrict__ emb,
                 const bf16* __restrict__ Wmat, const float* __restrict__ bih,
                 const bf16* __restrict__ Ust, const bf16* __restrict__ prevb,
                 bf16* __restrict__ XWout, float* __restrict__ dist)
{
    __shared__ __align__(16) bf16 As[2 * 128 * 32];   // 2 bufs x 8KB
    __shared__ __align__(16) bf16 Bs[2 * 128 * 32];

    const int tid = threadIdx.x;
    const int l  = tid & 63;
    const int w  = tid >> 6;
    const int wr = w >> 1, wc = w & 1;            // wave quadrant (64x64)
    const int wgid  = (blockIdx.x & 7) * 64 + (blockIdx.x >> 3);  // XCD swizzle
    const int mbase = (wgid >> 3) * 128;
    const int nbase = (wgid & 7) * 128;

    // staging geometry: wave w stages 16B chunks g0=w*128+l and g1=g0+64
    const int g0 = w * 128 + l;
    const int g1 = g0 + 64;
    const int r0 = g0 >> 2, c0 = (g0 & 3) * 16;   // row, byte-in-slice
    const int r1 = g1 >> 2, c1 = (g1 & 3) * 16;
    const char* Bsrc0 = (const char*)Wmat + (size_t)(nbase + r0) * 2048 + c0;
    const char* Bsrc1 = (const char*)Wmat + (size_t)(nbase + r1) * 2048 + c1;

    // fragment read bases: row=(l&15), k-chunk=(l>>4)*8 bf16
    const int frow = l & 15;
    const int kofs = (l >> 4) * 8;
    const bf16* Ard = As + (wr * 64 + frow) * 32 + kofs;
    const bf16* Brd = Bs + (wc * 64 + frow) * 32 + kofs;

    const int NS = MODE ? 10 : 1;

    auto stage = [&](int buf, int it) {
        const int s  = it >> 5;
        const int kb = (it & 31) << 6;            // K-slice byte offset
        const int ia = idx[s * 8192 + mbase + r0];
        const int ib = idx[s * 8192 + mbase + r1];
        const char* a0 = (const char*)emb + (size_t)ia * 2048 + c0 + kb;
        const char* a1 = (const char*)emb + (size_t)ib * 2048 + c1 + kb;
        bf16* As_ = As + buf * 4096 + w * 1024;   // wave-uniform dest (+lane*16 implicit)
        bf16* Bs_ = Bs + buf * 4096 + w * 1024;
        GLD_LDS16(a0, As_);
        GLD_LDS16(a1, As_ + 512);
        GLD_LDS16(Bsrc0 + kb, Bs_);
        GLD_LDS16(Bsrc1 + kb, Bs_ + 512);
    };

    stage(0, 0);
    asm volatile("s_waitcnt vmcnt(0)" ::: "memory");
    __syncthreads();
    int cur = 0;

    for (int s = 0; s < NS; ++s) {
        f32x4 acc[4][4] = {};
        for (int k = 0; k < 32; ++k) {
            const int it = s * 32 + k;
            if (it + 1 < NS * 32) stage(cur ^ 1, it + 1);   // prefetch next K-slice
            const bf16* Ab = Ard + cur * 4096;
            const bf16* Bb = Brd + cur * 4096;
            bf16x8 af[4], bfr[4];
            #pragma unroll
            for (int mt = 0; mt < 4; ++mt) af[mt]  = *(const bf16x8*)(Ab + mt * 16 * 32);
            #pragma unroll
            for (int nt = 0; nt < 4; ++nt) bfr[nt] = *(const bf16x8*)(Bb + nt * 16 * 32);
            #pragma unroll
            for (int mt = 0; mt < 4; ++mt)
                #pragma unroll
                for (int nt = 0; nt < 4; ++nt)
                    acc[mt][nt] = __builtin_amdgcn_mfma_f32_16x16x32_bf16(af[mt], bfr[nt], acc[mt][nt], 0, 0, 0);
            asm volatile("s_waitcnt vmcnt(0)" ::: "memory");  // next buf staged
            __syncthreads();
            cur ^= 1;
        }

        if (MODE == 0) {
            #pragma unroll
            for (int mt = 0; mt < 4; ++mt)
                #pragma unroll
                for (int nt = 0; nt < 4; ++nt) {
                    const int colg = nbase + wc * 64 + nt * 16 + frow;
                    const float bi = bih[colg];
                    #pragma unroll
                    for (int r = 0; r < 4; ++r) {
                        const int rowg = mbase + wr * 64 + mt * 16 + (l >> 4) * 4 + r;
                        XWout[(size_t)rowg * 1024 + colg] = (bf16)(acc[mt][nt][r] + bi);
                    }
                }
        } else {
            #pragma unroll
            for (int mt = 0; mt < 4; ++mt)
                #pragma unroll
                for (int r = 0; r < 4; ++r) {
                    const int rowg = mbase + wr * 64 + mt * 16 + (l >> 4) * 4 + r;
                    float p = 0.f;
                    #pragma unroll
                    for (int nt = 0; nt < 4; ++nt) {
                        const int colg = nbase + wc * 64 + nt * 16 + frow;
                        const size_t e = (size_t)rowg * 1024 + colg;
                        const float o = tanhf(acc[mt][nt][r] + (float)Ust[e]);
                        const float d = (float)prevb[e] - o + EPSC;
                        p += d * d;
                    }
                    #pragma unroll
                    for (int off = 1; off < 16; off <<= 1)
                        p += __shfl_xor(p, off, 16);
                    if (frow == 0) atomicAdd(&dist[s * 8192 + rowg], p);
                }
        }
    }
}

// ---------------- fused 128-step RNN: persistent, lean device-wide step barrier ----------------
// 64 wgs x 256 thr; wg owns 16 cols (Whh slice resident in ~128 VGPRs); wave w = batch rows
__global__ __launch_bounds__(256, 1)
void rnn_fused(bf16* __restrict__ raw, const bf16* __restrict__ Whh,
               const bf16* __restrict__ XWb, const float* __restrict__ bih,
               const float* __restrict__ bhh, bf16* __restrict__ Ust,
               int* __restrict__ cnt)
{
    const int tid  = threadIdx.x;
    const int l    = tid & 63;
    const int w    = tid >> 6;
    const int frow = l & 15;
    const int kofs = (l >> 4) * 8;
    const int j    = blockIdx.x * 16 + frow;

    bf16x8 Bf[32];                                 // Whh[j][:] fragments, resident all steps
    {
        const bf16* bp = Whh + (size_t)j * 1024 + kofs;
        #pragma unroll
        for (int kk = 0; kk < 32; ++kk) Bf[kk] = *(const bf16x8*)(bp + kk * 32);
    }
    const float bh = bhh[j];
    const float bi = bih[j];

    for (int t = 0; t < 128; ++t) {
        const bf16* Ap = raw + (size_t)t * 65536 + (size_t)(w * 16 + frow) * 1024 + kofs;
        f32x4 acc0 = {0.f,0.f,0.f,0.f}, acc1 = {0.f,0.f,0.f,0.f};
        #pragma unroll                              // FULL unroll: Bf[] statically indexed
        for (int kk = 0; kk < 32; kk += 2) {
            bf16x8 a0 = *(const bf16x8*)(Ap + kk * 32);
            bf16x8 a1 = *(const bf16x8*)(Ap + kk * 32 + 32);
            acc0 = __builtin_amdgcn_mfma_f32_16x16x32_bf16(a0, Bf[kk],     acc0, 0, 0, 0);
            acc1 = __builtin_amdgcn_mfma_f32_16x16x32_bf16(a1, Bf[kk + 1], acc1, 0, 0, 0);
        }
        bf16* rawN = raw + (size_t)(t + 1) * 65536;
        #pragma unroll
        for (int r = 0; r < 4; ++r) {
            const int b = w * 16 + (l >> 4) * 4 + r;
            const float V = acc0[r] + acc1[r] + bh;          // h_t @ W_hh^T + b_hh
            const size_t e = (size_t)(t * 64 + b) * 1024 + j;
            const float h = tanhf((float)XWb[e] + V);        // XWb holds +b_ih
            rawN[(size_t)b * 1024 + j] = (bf16)h;
            Ust[e] = (bf16)(V + bi);                         // hiddens_U + b_ih (phase D)
        }
        if (t < 127) {                                       // lean device-wide step barrier
            __syncthreads();                                 // drains vmcnt: stores in L2
            if (tid == 0) {
                // RELEASE: one wbl2 writeback, then signal
                __hip_atomic_fetch_add(&cnt[t], 1, __ATOMIC_RELEASE, __HIP_MEMORY_SCOPE_AGENT);
                // RELAXED polling: no cache-inv per poll
                while (__hip_atomic_load(&cnt[t], __ATOMIC_RELAXED, __HIP_MEMORY_SCOPE_AGENT) < 64)
                    __builtin_amdgcn_s_sleep(1);
            }
            __syncthreads();
            // one acquire fence per block: invalidate stale L1/L2 before reading raw[t+1]
            __builtin_amdgcn_fence(__ATOMIC_ACQUIRE, "agent");
        }
    }
}

// ---------------- pos term: (65/128) * sum (raw[t]-raw[t+1]+eps)^2 ----------------
__global__ void pos_kernel(const bf16* __restrict__ raw, float* __restrict__ lacc)
{
    float s = 0.f;
    const int NV = (128 * 64 * 1024) / 8;
    for (int i = blockIdx.x * blockDim.x + threadIdx.x; i < NV; i += gridDim.x * blockDim.x) {
        bf16x8 a = *(const bf16x8*)(raw + (size_t)i * 8);
        bf16x8 b = *(const bf16x8*)(raw + (size_t)i * 8 + 65536);
        #pragma unroll
        for (int j = 0; j < 8; ++j) {
            const float d = (float)a[j] - (float)b[j] + EPSC;
            s += d * d;
        }
    }
    #pragma unroll
    for (int off = 32; off > 0; off >>= 1) s += __shfl_down(s, off, 64);
    if ((threadIdx.x & 63) == 0) atomicAdd(lacc, s * (TEMPC / 128.f));
}

// ---------------- finalize: clip, exp, log, total ----------------
__global__ __launch_bounds__(1024)
void finalize_kernel(const float* __restrict__ dist, const float* __restrict__ lacc,
                     float* __restrict__ out)
{
    float s = 0.f;
    for (int r = threadIdx.x; r < 8192; r += 1024) {
        float se = 0.f;
        #pragma unroll
        for (int k = 0; k < 10; ++k) {
            float dd = dist[k * 8192 + r];
            dd = fminf(fmaxf(dd, 0.f), 0.01f);
            se += expf(-dd);
        }
        s += logf(se * (1.f / 8192.f) + EPSC);
    }
    #pragma unroll
    for (int off = 32; off > 0; off >>= 1) s += __shfl_down(s, off, 64);
    __shared__ float red[16];
    const int wave = threadIdx.x >> 6;
    if ((threadIdx.x & 63) == 0) red[wave] = s;
    __syncthreads();
    if (threadIdx.x == 0) {
        float tot = 0.f;
        #pragma unroll
        for (int i = 0; i < 16; ++i) tot += red[i];
        out[0] = tot + lacc[0];
    }
}

extern "C" void kernel_launch(void* const* d_in, const int* in_sizes, int n_in,
                              void* d_out, int out_size, void* d_ws, size_t ws_size,
                              hipStream_t stream)
{
    const int*   data    = (const int*)d_in[0];   // [128*64]
    const int*   samples = (const int*)d_in[1];   // [10*8192]
    const float* emb     = (const float*)d_in[2]; // [32000*1024]
    const float* Wih     = (const float*)d_in[3]; // [1024*1024]
    const float* bih     = (const float*)d_in[4]; // [1024]
    const float* Whh     = (const float*)d_in[5]; // [1024*1024]
    const float* bhh     = (const float*)d_in[6]; // [1024]

    char* ws = (char*)d_ws;
    size_t off = 0;
    auto alloc = [&](size_t bytes) { void* p = ws + off; off += (bytes + 255) & ~(size_t)255; return p; };
    bf16*  emb_b = (bf16*)alloc((size_t)32000 * 1024 * 2);
    bf16*  Wih_b = (bf16*)alloc((size_t)1024 * 1024 * 2);
    bf16*  Whh_b = (bf16*)alloc((size_t)1024 * 1024 * 2);
    bf16*  XWb   = (bf16*)alloc((size_t)8192 * 1024 * 2);
    bf16*  Ust   = (bf16*)alloc((size_t)8192 * 1024 * 2);
    bf16*  raw   = (bf16*)alloc((size_t)129 * 64 * 1024 * 2);
    float* dist  = (float*)alloc((size_t)10 * 8192 * 4);
    float* lacc  = (float*)alloc(256);
    int*   cnt   = (int*)alloc(128 * 4);

    hipMemsetAsync(raw,  0, 64 * 1024 * 2, stream);   // h0 = 0 (raw[0])
    hipMemsetAsync(dist, 0, 10 * 8192 * 4, stream);
    hipMemsetAsync(lacc, 0, 256, stream);
    hipMemsetAsync(cnt,  0, 128 * 4, stream);         // step-barrier counters

    conv_kernel<<<2048, 256, 0, stream>>>(emb, emb_b, 32000 * 1024);
    conv_kernel<<<512, 256, 0, stream>>>(Wih, Wih_b, 1024 * 1024);
    conv_kernel<<<512, 256, 0, stream>>>(Whh, Whh_b, 1024 * 1024);

    // Phase A: XWb = emb[data] @ Wih^T + bih  (bf16)
    gemm_kernel<0><<<512, 256, 0, stream>>>(data, emb_b, Wih_b, bih,
                                            nullptr, nullptr, XWb, nullptr);
    // Phase B: all 128 RNN steps in one persistent kernel
    rnn_fused<<<64, 256, 0, stream>>>(raw, Whh_b, XWb, bih, bhh, Ust, cnt);

    // pos term
    pos_kernel<<<512, 256, 0, stream>>>(raw, lacc);

    // Phase D: sampled negatives GEMM + fused dist epilogue
    gemm_kernel<1><<<512, 256, 0, stream>>>(samples, emb_b, Wih_b, bih,
                                            Ust, raw, nullptr, dist);

    finalize_kernel<<<1, 1024, 0, stream>>>(dist, lacc, (float*)d_out);
}

// Round 4
// 1755.595 us; speedup vs baseline: 1.4309x; 1.3315x over previous
//
#include <hip/hip_runtime.h>
#include <hip/hip_bf16.h>
#include <cmath>

typedef __bf16 bf16;
typedef __attribute__((ext_vector_type(8))) __bf16 bf16x8;
typedef __attribute__((ext_vector_type(4))) __bf16 bf16x4;
typedef __attribute__((ext_vector_type(4))) float f32x4;

#define TEMPC 65.0f
#define EPSC 1e-6f

#define GLD_LDS16(gptr, lptr)                                                             \
    __builtin_amdgcn_global_load_lds(                                                     \
        (const __attribute__((address_space(1))) unsigned int*)(gptr),                    \
        (__attribute__((address_space(3))) unsigned int*)(lptr), 16, 0, 0)

// ---------------- f32 -> bf16 convert ----------------
__global__ void conv_kernel(const float* __restrict__ s, bf16* __restrict__ d, int n)
{
    int i = (blockIdx.x * blockDim.x + threadIdx.x) * 4;
    const int stride = gridDim.x * blockDim.x * 4;
    for (; i < n; i += stride) {
        const float4 v = *(const float4*)(s + i);
        bf16x4 o;
        o[0] = (bf16)v.x; o[1] = (bf16)v.y; o[2] = (bf16)v.z; o[3] = (bf16)v.w;
        *(bf16x4*)(d + i) = o;
    }
}

// ---------------- 2-phase pipelined MFMA GEMM: gathered-A [128 rows] @ W^T ----------------
// 128x128 C-tile, BK=32, double-buffered LDS, global_load_lds width-16 staging.
// MODE 0: store XW = acc + b_ih (bf16)    MODE 1: 10-sample loop; fused dist epilogue
template<int MODE>
__global__ __launch_bounds__(256)
void gemm_kernel(const int* __restrict__ idx, const bf16* __restrict__ emb,
                 const bf16* __restrict__ Wmat, const float* __restrict__ bih,
                 const bf16* __restrict__ Ust, const bf16* __restrict__ prevb,
                 bf16* __restrict__ XWout, float* __restrict__ dist)
{
    __shared__ __align__(16) bf16 As[2 * 128 * 32];   // 2 bufs x 8KB
    __shared__ __align__(16) bf16 Bs[2 * 128 * 32];

    const int tid = threadIdx.x;
    const int l  = tid & 63;
    const int w  = tid >> 6;
    const int wr = w >> 1, wc = w & 1;            // wave quadrant (64x64)
    const int wgid  = (blockIdx.x & 7) * 64 + (blockIdx.x >> 3);  // XCD swizzle
    const int mbase = (wgid >> 3) * 128;
    const int nbase = (wgid & 7) * 128;

    // staging geometry: wave w stages 16B chunks g0=w*128+l and g1=g0+64
    const int g0 = w * 128 + l;
    const int g1 = g0 + 64;
    const int r0 = g0 >> 2, c0 = (g0 & 3) * 16;   // row, byte-in-slice
    const int r1 = g1 >> 2, c1 = (g1 & 3) * 16;
    const char* Bsrc0 = (const char*)Wmat + (size_t)(nbase + r0) * 2048 + c0;
    const char* Bsrc1 = (const char*)Wmat + (size_t)(nbase + r1) * 2048 + c1;

    // fragment read bases: row=(l&15), k-chunk=(l>>4)*8 bf16
    const int frow = l & 15;
    const int kofs = (l >> 4) * 8;
    const bf16* Ard = As + (wr * 64 + frow) * 32 + kofs;
    const bf16* Brd = Bs + (wc * 64 + frow) * 32 + kofs;

    const int NS = MODE ? 10 : 1;

    // current-sample A source pointers (idx loads hoisted out of K-loop)
    const char* a0p = (const char*)emb + (size_t)idx[mbase + r0] * 2048 + c0;
    const char* a1p = (const char*)emb + (size_t)idx[mbase + r1] * 2048 + c1;

    auto stage_k = [&](int buf, const char* pa0, const char* pa1, int kb) {
        bf16* As_ = As + buf * 4096 + w * 1024;   // wave-uniform dest (+lane*16 implicit)
        bf16* Bs_ = Bs + buf * 4096 + w * 1024;
        GLD_LDS16(pa0 + kb, As_);
        GLD_LDS16(pa1 + kb, As_ + 512);
        GLD_LDS16(Bsrc0 + kb, Bs_);
        GLD_LDS16(Bsrc1 + kb, Bs_ + 512);
    };

    stage_k(0, a0p, a1p, 0);
    asm volatile("s_waitcnt vmcnt(0)" ::: "memory");
    __syncthreads();
    int cur = 0;

    for (int s = 0; s < NS; ++s) {
        f32x4 acc[4][4] = {};
        for (int k = 0; k < 32; ++k) {
            if (k < 31) {
                stage_k(cur ^ 1, a0p, a1p, (k + 1) << 6);       // next K-slice, same sample
            } else if (s + 1 < NS) {
                a0p = (const char*)emb + (size_t)idx[(s + 1) * 8192 + mbase + r0] * 2048 + c0;
                a1p = (const char*)emb + (size_t)idx[(s + 1) * 8192 + mbase + r1] * 2048 + c1;
                stage_k(cur ^ 1, a0p, a1p, 0);                   // first slice, next sample
            }
            const bf16* Ab = Ard + cur * 4096;
            const bf16* Bb = Brd + cur * 4096;
            bf16x8 af[4], bfr[4];
            #pragma unroll
            for (int mt = 0; mt < 4; ++mt) af[mt]  = *(const bf16x8*)(Ab + mt * 16 * 32);
            #pragma unroll
            for (int nt = 0; nt < 4; ++nt) bfr[nt] = *(const bf16x8*)(Bb + nt * 16 * 32);
            #pragma unroll
            for (int mt = 0; mt < 4; ++mt)
                #pragma unroll
                for (int nt = 0; nt < 4; ++nt)
                    acc[mt][nt] = __builtin_amdgcn_mfma_f32_16x16x32_bf16(af[mt], bfr[nt], acc[mt][nt], 0, 0, 0);
            asm volatile("s_waitcnt vmcnt(0)" ::: "memory");  // next buf staged
            __syncthreads();
            cur ^= 1;
        }

        if (MODE == 0) {
            #pragma unroll
            for (int mt = 0; mt < 4; ++mt)
                #pragma unroll
                for (int nt = 0; nt < 4; ++nt) {
                    const int colg = nbase + wc * 64 + nt * 16 + frow;
                    const float bi = bih[colg];
                    #pragma unroll
                    for (int r = 0; r < 4; ++r) {
                        const int rowg = mbase + wr * 64 + mt * 16 + (l >> 4) * 4 + r;
                        XWout[(size_t)rowg * 1024 + colg] = (bf16)(acc[mt][nt][r] + bi);
                    }
                }
        } else {
            #pragma unroll
            for (int mt = 0; mt < 4; ++mt)
                #pragma unroll
                for (int r = 0; r < 4; ++r) {
                    const int rowg = mbase + wr * 64 + mt * 16 + (l >> 4) * 4 + r;
                    float p = 0.f;
                    #pragma unroll
                    for (int nt = 0; nt < 4; ++nt) {
                        const int colg = nbase + wc * 64 + nt * 16 + frow;
                        const size_t e = (size_t)rowg * 1024 + colg;
                        const float o = tanhf(acc[mt][nt][r] + (float)Ust[e]);
                        const float d = (float)prevb[e] - o + EPSC;
                        p += d * d;
                    }
                    #pragma unroll
                    for (int off = 1; off < 16; off <<= 1)
                        p += __shfl_xor(p, off, 16);
                    if (frow == 0) atomicAdd(&dist[s * 8192 + rowg], p);
                }
        }
    }
}

// ---------------- fused 128-step RNN: 8 independent batch-groups x 32 blocks ----------------
// Block (group=bid&7, slot=bid>>3): owns j-slice [slot*32, slot*32+32) for batch rows
// [group*8, group*8+8). Whh slice LDS-resident (64KB, loaded once). Per step: one
// 32-block group barrier (release/acquire agent scope -> correct on any XCD placement).
__global__ __launch_bounds__(128, 1)
void rnn_fused(bf16* __restrict__ raw, const bf16* __restrict__ Whh,
               const bf16* __restrict__ XWb, const float* __restrict__ bih,
               const float* __restrict__ bhh, bf16* __restrict__ Ust,
               int* __restrict__ cnt)
{
    __shared__ __align__(16) bf16 Wlds[32 * 1024];   // 64KB: [kk 32][jt 2][frow 16][kc 32]

    const int tid    = threadIdx.x;
    const int l      = tid & 63;
    const int w      = tid >> 6;            // wave = j-tile (0,1)
    const int group  = blockIdx.x & 7;      // batch group (XCD-aligned if round-robin)
    const int slot   = blockIdx.x >> 3;     // j-slice within group
    const int jbase  = slot * 32;
    const int frow   = l & 15;
    const int kchunk = l >> 4;
    const int jglob  = jbase + w * 16 + frow;

    // Stage Whh j-slice into LDS once: chunk (kk, jt=w) = 16 rows x 64B, lane l -> +l*16
    {
        const char* gsrc = (const char*)Whh + (size_t)(jbase + w * 16 + (l >> 2)) * 2048 + (l & 3) * 16;
        for (int kk = 0; kk < 32; ++kk)
            GLD_LDS16(gsrc + kk * 64, Wlds + (kk * 2 + w) * 512);
        asm volatile("s_waitcnt vmcnt(0)" ::: "memory");
        __syncthreads();
    }
    const float bh = bhh[jglob];
    const float bi = bih[jglob];

    const bf16* hbase = raw + (size_t)(group * 8 + (frow & 7)) * 1024 + kchunk * 8;
    const bf16* wrd   = Wlds + w * 512 + frow * 32 + kchunk * 8;   // +kk*1024 per k-block

    for (int t = 0; t < 128; ++t) {
        if (t > 0) {
            if (tid == 0)
                while (__hip_atomic_load(&cnt[(t * 8 + group) * 16], __ATOMIC_RELAXED,
                                         __HIP_MEMORY_SCOPE_AGENT) < 32)
                    __builtin_amdgcn_s_sleep(2);
            __syncthreads();
            __builtin_amdgcn_fence(__ATOMIC_ACQUIRE, "agent");     // inv: see group's h stores
        }
        // XWb for this step (row-clamped so lanes>=32 stay in bounds; they don't store)
        float xw[4];
        #pragma unroll
        for (int r = 0; r < 4; ++r) {
            const int bc = ((l >> 4) * 4 + r) & 7;
            xw[r] = (float)XWb[(size_t)(t * 64 + group * 8 + bc) * 1024 + jglob];
        }
        // h_t fragments: 32 x 16B loads, all in flight (A rows 8-15 duplicate 0-7; discarded)
        const bf16* hp = hbase + (size_t)t * 65536;
        bf16x8 af[32];
        #pragma unroll
        for (int kk = 0; kk < 32; ++kk) af[kk] = *(const bf16x8*)(hp + kk * 32);

        f32x4 acc = {0.f, 0.f, 0.f, 0.f};
        #pragma unroll
        for (int kk = 0; kk < 32; ++kk)
            acc = __builtin_amdgcn_mfma_f32_16x16x32_bf16(
                      af[kk], *(const bf16x8*)(wrd + kk * 1024), acc, 0, 0, 0);

        bf16* rawN = raw + (size_t)(t + 1) * 65536;
        if (l < 32) {                               // rows 0-7 only
            #pragma unroll
            for (int r = 0; r < 4; ++r) {
                const int b = (l >> 4) * 4 + r;
                const float V = acc[r] + bh;                        // h @ Whh^T + b_hh
                const float h = tanhf(xw[r] + V);
                const size_t row = (size_t)(t * 64 + group * 8 + b);
                rawN[(size_t)(group * 8 + b) * 1024 + jglob] = (bf16)h;
                Ust[row * 1024 + jglob] = (bf16)(V + bi);
            }
        }
        if (t < 127) {
            __syncthreads();                        // vmcnt-drained stores
            if (tid == 0)
                __hip_atomic_fetch_add(&cnt[((t + 1) * 8 + group) * 16], 1,
                                       __ATOMIC_RELEASE, __HIP_MEMORY_SCOPE_AGENT);
        }
    }
}

// ---------------- pos term: (65/128) * sum (raw[t]-raw[t+1]+eps)^2 ----------------
__global__ void pos_kernel(const bf16* __restrict__ raw, float* __restrict__ lacc)
{
    float s = 0.f;
    const int NV = (128 * 64 * 1024) / 8;
    for (int i = blockIdx.x * blockDim.x + threadIdx.x; i < NV; i += gridDim.x * blockDim.x) {
        bf16x8 a = *(const bf16x8*)(raw + (size_t)i * 8);
        bf16x8 b = *(const bf16x8*)(raw + (size_t)i * 8 + 65536);
        #pragma unroll
        for (int j = 0; j < 8; ++j) {
            const float d = (float)a[j] - (float)b[j] + EPSC;
            s += d * d;
        }
    }
    #pragma unroll
    for (int off = 32; off > 0; off >>= 1) s += __shfl_down(s, off, 64);
    if ((threadIdx.x & 63) == 0) atomicAdd(lacc, s * (TEMPC / 128.f));
}

// ---------------- finalize: clip, exp, log, total ----------------
__global__ __launch_bounds__(1024)
void finalize_kernel(const float* __restrict__ dist, const float* __restrict__ lacc,
                     float* __restrict__ out)
{
    float s = 0.f;
    for (int r = threadIdx.x; r < 8192; r += 1024) {
        float se = 0.f;
        #pragma unroll
        for (int k = 0; k < 10; ++k) {
            float dd = dist[k * 8192 + r];
            dd = fminf(fmaxf(dd, 0.f), 0.01f);
            se += expf(-dd);
        }
        s += logf(se * (1.f / 8192.f) + EPSC);
    }
    #pragma unroll
    for (int off = 32; off > 0; off >>= 1) s += __shfl_down(s, off, 64);
    __shared__ float red[16];
    const int wave = threadIdx.x >> 6;
    if ((threadIdx.x & 63) == 0) red[wave] = s;
    __syncthreads();
    if (threadIdx.x == 0) {
        float tot = 0.f;
        #pragma unroll
        for (int i = 0; i < 16; ++i) tot += red[i];
        out[0] = tot + lacc[0];
    }
}

extern "C" void kernel_launch(void* const* d_in, const int* in_sizes, int n_in,
                              void* d_out, int out_size, void* d_ws, size_t ws_size,
                              hipStream_t stream)
{
    const int*   data    = (const int*)d_in[0];   // [128*64]
    const int*   samples = (const int*)d_in[1];   // [10*8192]
    const float* emb     = (const float*)d_in[2]; // [32000*1024]
    const float* Wih     = (const float*)d_in[3]; // [1024*1024]
    const float* bih     = (const float*)d_in[4]; // [1024]
    const float* Whh     = (const float*)d_in[5]; // [1024*1024]
    const float* bhh     = (const float*)d_in[6]; // [1024]

    char* ws = (char*)d_ws;
    size_t off = 0;
    auto alloc = [&](size_t bytes) { void* p = ws + off; off += (bytes + 255) & ~(size_t)255; return p; };
    bf16*  emb_b = (bf16*)alloc((size_t)32000 * 1024 * 2);
    bf16*  Wih_b = (bf16*)alloc((size_t)1024 * 1024 * 2);
    bf16*  Whh_b = (bf16*)alloc((size_t)1024 * 1024 * 2);
    bf16*  XWb   = (bf16*)alloc((size_t)8192 * 1024 * 2);
    bf16*  Ust   = (bf16*)alloc((size_t)8192 * 1024 * 2);
    bf16*  raw   = (bf16*)alloc((size_t)129 * 64 * 1024 * 2);
    float* dist  = (float*)alloc((size_t)10 * 8192 * 4);
    float* lacc  = (float*)alloc(256);
    int*   cnt   = (int*)alloc(65536);

    hipMemsetAsync(raw,  0, 64 * 1024 * 2, stream);   // h0 = 0 (raw[0])
    hipMemsetAsync(dist, 0, 10 * 8192 * 4, stream);
    hipMemsetAsync(lacc, 0, 256, stream);
    hipMemsetAsync(cnt,  0, 65536, stream);           // per-(step,group) barrier counters

    conv_kernel<<<2048, 256, 0, stream>>>(emb, emb_b, 32000 * 1024);
    conv_kernel<<<512, 256, 0, stream>>>(Wih, Wih_b, 1024 * 1024);
    conv_kernel<<<512, 256, 0, stream>>>(Whh, Whh_b, 1024 * 1024);

    // Phase A: XWb = emb[data] @ Wih^T + bih  (bf16)
    gemm_kernel<0><<<512, 256, 0, stream>>>(data, emb_b, Wih_b, bih,
                                            nullptr, nullptr, XWb, nullptr);
    // Phase B: all 128 RNN steps, 8 groups x 32 blocks, LDS-resident weights
    rnn_fused<<<256, 128, 0, stream>>>(raw, Whh_b, XWb, bih, bhh, Ust, cnt);

    // pos term
    pos_kernel<<<512, 256, 0, stream>>>(raw, lacc);

    // Phase D: sampled negatives GEMM + fused dist epilogue
    gemm_kernel<1><<<512, 256, 0, stream>>>(samples, emb_b, Wih_b, bih,
                                            Ust, raw, nullptr, dist);

    finalize_kernel<<<1, 1024, 0, stream>>>(dist, lacc, (float*)d_out);
}

// Round 5
// 1361.735 us; speedup vs baseline: 1.8447x; 1.2892x over previous
//
#include <hip/hip_runtime.h>
#include <hip/hip_bf16.h>
#include <cmath>

typedef __bf16 bf16;
typedef __attribute__((ext_vector_type(8))) __bf16 bf16x8;
typedef __attribute__((ext_vector_type(4))) __bf16 bf16x4;
typedef __attribute__((ext_vector_type(4))) float f32x4;
typedef unsigned long long ull;

#define TEMPC 65.0f
#define EPSC 1e-6f

#define GLD_LDS16(gptr, lptr)                                                             \
    __builtin_amdgcn_global_load_lds(                                                     \
        (const __attribute__((address_space(1))) unsigned int*)(gptr),                    \
        (__attribute__((address_space(3))) unsigned int*)(lptr), 16, 0, 0)

// ---------------- f32 -> bf16 convert ----------------
__global__ void conv_kernel(const float* __restrict__ s, bf16* __restrict__ d, int n)
{
    int i = (blockIdx.x * blockDim.x + threadIdx.x) * 4;
    const int stride = gridDim.x * blockDim.x * 4;
    for (; i < n; i += stride) {
        const float4 v = *(const float4*)(s + i);
        bf16x4 o;
        o[0] = (bf16)v.x; o[1] = (bf16)v.y; o[2] = (bf16)v.z; o[3] = (bf16)v.w;
        *(bf16x4*)(d + i) = o;
    }
}

// ---------------- depth-2 pipelined MFMA GEMM: gathered-A [128 rows] @ W^T ----------------
// 128x128 C-tile, BK=32, double-buffered LDS, counted vmcnt(4) (2 K-steps in flight),
// LDS read-conflict fix via pre-swizzled global source (kc ^= (row>>1)&3).
// MODE 0: grid 512, store XW = acc + b_ih (bf16).  MODE 1: grid 5120 (s flattened),
// fused dist epilogue.
template<int MODE>
__global__ __launch_bounds__(256)
void gemm_kernel(const int* __restrict__ idx, const bf16* __restrict__ emb,
                 const bf16* __restrict__ Wmat, const float* __restrict__ bih,
                 const bf16* __restrict__ Ust, const bf16* __restrict__ prevb,
                 bf16* __restrict__ XWout, float* __restrict__ dist)
{
    __shared__ __align__(16) bf16 As[2 * 128 * 32];   // 2 bufs x 8KB
    __shared__ __align__(16) bf16 Bs[2 * 128 * 32];

    const int tid = threadIdx.x;
    const int l  = tid & 63;
    const int w  = tid >> 6;
    const int wr = w >> 1, wc = w & 1;                // wave quadrant (64x64)

    int s, within;
    if (MODE == 0) {
        const int wg = (blockIdx.x & 7) * 64 + (blockIdx.x >> 3);   // XCD swizzle (512%8==0)
        s = 0; within = wg;
    } else {
        const int wg = (blockIdx.x & 7) * 640 + (blockIdx.x >> 3);  // XCD swizzle (5120%8==0)
        s = wg >> 9; within = wg & 511;
    }
    const int mbase = (within >> 3) * 128;
    const int nbase = (within & 7) * 128;

    // staging geometry: wave w stages 16B chunks g0=w*128+l, g1=g0+64 (A and B)
    // LDS slot is linear (chunk*16B); global source col pre-swizzled so that the
    // fragment read (below) is ~2-way bank-conflict-free.
    const int r0 = w * 32 + (l >> 2);                 // rows r0, r0+16
    const int csw = ((l & 3) ^ ((l >> 3) & 3)) * 16;  // swizzled 16B sub-chunk
    const char* Bsrc0 = (const char*)Wmat + (size_t)(nbase + r0) * 2048 + csw;
    const char* Bsrc1 = (const char*)Wmat + (size_t)(nbase + r0 + 16) * 2048 + csw;
    const char* Asrc0 = (const char*)emb + (size_t)idx[s * 8192 + mbase + r0] * 2048 + csw;
    const char* Asrc1 = (const char*)emb + (size_t)idx[s * 8192 + mbase + r0 + 16] * 2048 + csw;

    // fragment read bases: row=(l&15), k-chunk swizzled by (row>>1)&3
    const int frow  = l & 15;
    const int koffE = (((l >> 4) ^ ((frow >> 1) & 3)) * 8);   // element offset in 32-el row
    const bf16* Ard = As + (wr * 64 + frow) * 32 + koffE;
    const bf16* Brd = Bs + (wc * 64 + frow) * 32 + koffE;

    auto stage = [&](int buf, int kb) {
        bf16* As_ = As + buf * 4096 + w * 1024;       // wave-uniform dest (+lane*16 implicit)
        bf16* Bs_ = Bs + buf * 4096 + w * 1024;
        GLD_LDS16(Asrc0 + kb, As_);
        GLD_LDS16(Asrc1 + kb, As_ + 512);
        GLD_LDS16(Bsrc0 + kb, Bs_);
        GLD_LDS16(Bsrc1 + kb, Bs_ + 512);
    };

    stage(0, 0);
    stage(1, 64);

    f32x4 acc[4][4] = {};
    for (int k = 0; k < 32; ++k) {
        if (k == 31) asm volatile("s_waitcnt vmcnt(0)" ::: "memory");
        else         asm volatile("s_waitcnt vmcnt(4)" ::: "memory");  // buf k ready, k+1 flying
        __syncthreads();
        const bf16* Ab = Ard + (k & 1) * 4096;
        const bf16* Bb = Brd + (k & 1) * 4096;
        bf16x8 af[4], bfr[4];
        #pragma unroll
        for (int mt = 0; mt < 4; ++mt) af[mt]  = *(const bf16x8*)(Ab + mt * 16 * 32);
        #pragma unroll
        for (int nt = 0; nt < 4; ++nt) bfr[nt] = *(const bf16x8*)(Bb + nt * 16 * 32);
        #pragma unroll
        for (int mt = 0; mt < 4; ++mt)
            #pragma unroll
            for (int nt = 0; nt < 4; ++nt)
                acc[mt][nt] = __builtin_amdgcn_mfma_f32_16x16x32_bf16(af[mt], bfr[nt], acc[mt][nt], 0, 0, 0);
        __syncthreads();                                  // all waves done reading buf k
        if (k + 2 < 32) stage(k & 1, (k + 2) * 64);       // refill buf k with step k+2
    }

    if (MODE == 0) {
        #pragma unroll
        for (int mt = 0; mt < 4; ++mt)
            #pragma unroll
            for (int nt = 0; nt < 4; ++nt) {
                const int colg = nbase + wc * 64 + nt * 16 + frow;
                const float bi = bih[colg];
                #pragma unroll
                for (int r = 0; r < 4; ++r) {
                    const int rowg = mbase + wr * 64 + mt * 16 + (l >> 4) * 4 + r;
                    XWout[(size_t)rowg * 1024 + colg] = (bf16)(acc[mt][nt][r] + bi);
                }
            }
    } else {
        #pragma unroll
        for (int mt = 0; mt < 4; ++mt)
            #pragma unroll
            for (int r = 0; r < 4; ++r) {
                const int rowg = mbase + wr * 64 + mt * 16 + (l >> 4) * 4 + r;
                float p = 0.f;
                #pragma unroll
                for (int nt = 0; nt < 4; ++nt) {
                    const int colg = nbase + wc * 64 + nt * 16 + frow;
                    const size_t e = (size_t)rowg * 1024 + colg;
                    const float o = tanhf(acc[mt][nt][r] + (float)Ust[e]);
                    const float d = (float)prevb[e] - o + EPSC;
                    p += d * d;
                }
                #pragma unroll
                for (int off = 1; off < 16; off <<= 1)
                    p += __shfl_xor(p, off, 16);
                if (frow == 0) atomicAdd(&dist[s * 8192 + rowg], p);
            }
    }
}

// ---------------- fused 128-step RNN: point-coherent h exchange, no cache flush/inv ----
// 256 blocks x 128 thr (1/CU). Block (group=bid&7, slot=bid>>3): batch rows
// [group*8,group*8+8), j-cols [slot*32, slot*32+32). Whh slice LDS-resident (64KB,
// swizzled). h stored/loaded via agent-scope relaxed atomics (coherent point), so the
// per-step barrier needs NO wbl2-heavy acquire fence.
__global__ __launch_bounds__(128, 1)
void rnn_fused(bf16* __restrict__ raw, const bf16* __restrict__ Whh,
               const bf16* __restrict__ XWb, const float* __restrict__ bih,
               const float* __restrict__ bhh, bf16* __restrict__ Ust,
               int* __restrict__ cnt)
{
    __shared__ __align__(16) bf16 Wlds[32 * 1024];   // 64KB: chunk(kk,w)=1KB of [j16][kc4]

    const int tid    = threadIdx.x;
    const int l      = tid & 63;
    const int w      = tid >> 6;            // wave = j-tile (0,1)
    const int group  = blockIdx.x & 7;      // batch group
    const int slot   = blockIdx.x >> 3;     // j-slice within group
    const int jbase  = slot * 32;
    const int frow   = l & 15;
    const int kchunk = l >> 4;
    const int jglob  = jbase + w * 16 + frow;

    // Stage Whh j-slice into LDS once, source pre-swizzled (kc ^= (j>>1)&3)
    {
        const int jloc = l >> 2;
        const int csw  = ((l & 3) ^ ((l >> 3) & 3)) * 16;
        const char* gsrc = (const char*)Whh + (size_t)(jbase + w * 16 + jloc) * 2048 + csw;
        for (int kk = 0; kk < 32; ++kk)
            GLD_LDS16(gsrc + kk * 64, Wlds + (kk * 2 + w) * 512);
        asm volatile("s_waitcnt vmcnt(0)" ::: "memory");
        __syncthreads();
    }
    const float bh = bhh[jglob];
    const float bi = bih[jglob];

    // swizzled fragment read base; +kk*1024 elements per k-block
    const int ksw   = kchunk ^ ((frow >> 1) & 3);
    const bf16* wrd = Wlds + w * 512 + frow * 32 + ksw * 8;

    for (int t = 0; t < 128; ++t) {
        if (t > 0) {
            if (tid == 0)
                while (__hip_atomic_load(&cnt[(t * 8 + group) * 16], __ATOMIC_RELAXED,
                                         __HIP_MEMORY_SCOPE_AGENT) < 32)
                    __builtin_amdgcn_s_sleep(2);
            __syncthreads();
        }
        // XWb for this step (L2-hot: no cache inv in this design)
        float xw[4];
        #pragma unroll
        for (int r = 0; r < 4; ++r) {
            const int bc = ((l >> 4) * 4 + r) & 7;
            xw[r] = (float)XWb[(size_t)(t * 64 + group * 8 + bc) * 1024 + jglob];
        }
        // h_t fragments via coherent 8B atomic loads (bypass stale L2)
        const ull* hp = (const ull*)(raw + (size_t)t * 65536 +
                                     (size_t)(group * 8 + (frow & 7)) * 1024 + kchunk * 8);
        f32x4 acc = {0.f, 0.f, 0.f, 0.f};
        #pragma unroll
        for (int kk = 0; kk < 32; ++kk) {
            union { ull u[2]; bf16x8 v; } cvt;
            cvt.u[0] = __hip_atomic_load(hp + (size_t)kk * 8,     __ATOMIC_RELAXED, __HIP_MEMORY_SCOPE_AGENT);
            cvt.u[1] = __hip_atomic_load(hp + (size_t)kk * 8 + 1, __ATOMIC_RELAXED, __HIP_MEMORY_SCOPE_AGENT);
            acc = __builtin_amdgcn_mfma_f32_16x16x32_bf16(
                      cvt.v, *(const bf16x8*)(wrd + kk * 1024), acc, 0, 0, 0);
        }

        bf16* rawN = raw + (size_t)(t + 1) * 65536;
        if (l < 32) {                               // rows 0-7 real
            #pragma unroll
            for (int r = 0; r < 4; ++r) {
                const int b = (l >> 4) * 4 + r;
                const float V = acc[r] + bh;                        // h @ Whh^T + b_hh
                const float h = tanhf(xw[r] + V);
                const size_t row = (size_t)(t * 64 + group * 8 + b);
                Ust[row * 1024 + jglob] = (bf16)(V + bi);           // normal store (read next kernel)
                // pack (jglob, jglob+1) into one int; even-frow lanes store coherently
                const bf16 hb = (bf16)h;
                unsigned short hs = __builtin_bit_cast(unsigned short, hb);
                unsigned short hn = (unsigned short)__shfl_down((int)hs, 1, 64);
                if ((frow & 1) == 0) {
                    unsigned int pack = (unsigned int)hs | ((unsigned int)hn << 16);
                    unsigned int* dst = (unsigned int*)(rawN + (size_t)(group * 8 + b) * 1024 + jglob);
                    __hip_atomic_store(dst, pack, __ATOMIC_RELAXED, __HIP_MEMORY_SCOPE_AGENT);
                }
            }
        }
        if (t < 127) {
            __syncthreads();                        // compiler drains vmcnt before s_barrier
            if (tid == 0)
                __hip_atomic_fetch_add(&cnt[((t + 1) * 8 + group) * 16], 1,
                                       __ATOMIC_RELEASE, __HIP_MEMORY_SCOPE_AGENT);
        }
    }
}

// ---------------- pos term: (65/128) * sum (raw[t]-raw[t+1]+eps)^2 ----------------
__global__ void pos_kernel(const bf16* __restrict__ raw, float* __restrict__ lacc)
{
    float s = 0.f;
    const int NV = (128 * 64 * 1024) / 8;
    for (int i = blockIdx.x * blockDim.x + threadIdx.x; i < NV; i += gridDim.x * blockDim.x) {
        bf16x8 a = *(const bf16x8*)(raw + (size_t)i * 8);
        bf16x8 b = *(const bf16x8*)(raw + (size_t)i * 8 + 65536);
        #pragma unroll
        for (int j = 0; j < 8; ++j) {
            const float d = (float)a[j] - (float)b[j] + EPSC;
            s += d * d;
        }
    }
    #pragma unroll
    for (int off = 32; off > 0; off >>= 1) s += __shfl_down(s, off, 64);
    if ((threadIdx.x & 63) == 0) atomicAdd(lacc, s * (TEMPC / 128.f));
}

// ---------------- finalize: clip, exp, log, total ----------------
__global__ __launch_bounds__(1024)
void finalize_kernel(const float* __restrict__ dist, const float* __restrict__ lacc,
                     float* __restrict__ out)
{
    float s = 0.f;
    for (int r = threadIdx.x; r < 8192; r += 1024) {
        float se = 0.f;
        #pragma unroll
        for (int k = 0; k < 10; ++k) {
            float dd = dist[k * 8192 + r];
            dd = fminf(fmaxf(dd, 0.f), 0.01f);
            se += expf(-dd);
        }
        s += logf(se * (1.f / 8192.f) + EPSC);
    }
    #pragma unroll
    for (int off = 32; off > 0; off >>= 1) s += __shfl_down(s, off, 64);
    __shared__ float red[16];
    const int wave = threadIdx.x >> 6;
    if ((threadIdx.x & 63) == 0) red[wave] = s;
    __syncthreads();
    if (threadIdx.x == 0) {
        float tot = 0.f;
        #pragma unroll
        for (int i = 0; i < 16; ++i) tot += red[i];
        out[0] = tot + lacc[0];
    }
}

extern "C" void kernel_launch(void* const* d_in, const int* in_sizes, int n_in,
                              void* d_out, int out_size, void* d_ws, size_t ws_size,
                              hipStream_t stream)
{
    const int*   data    = (const int*)d_in[0];   // [128*64]
    const int*   samples = (const int*)d_in[1];   // [10*8192]
    const float* emb     = (const float*)d_in[2]; // [32000*1024]
    const float* Wih     = (const float*)d_in[3]; // [1024*1024]
    const float* bih     = (const float*)d_in[4]; // [1024]
    const float* Whh     = (const float*)d_in[5]; // [1024*1024]
    const float* bhh     = (const float*)d_in[6]; // [1024]

    char* ws = (char*)d_ws;
    size_t off = 0;
    auto alloc = [&](size_t bytes) { void* p = ws + off; off += (bytes + 255) & ~(size_t)255; return p; };
    bf16*  emb_b = (bf16*)alloc((size_t)32000 * 1024 * 2);
    bf16*  Wih_b = (bf16*)alloc((size_t)1024 * 1024 * 2);
    bf16*  Whh_b = (bf16*)alloc((size_t)1024 * 1024 * 2);
    bf16*  XWb   = (bf16*)alloc((size_t)8192 * 1024 * 2);
    bf16*  Ust   = (bf16*)alloc((size_t)8192 * 1024 * 2);
    bf16*  raw   = (bf16*)alloc((size_t)129 * 64 * 1024 * 2);
    float* dist  = (float*)alloc((size_t)10 * 8192 * 4);
    float* lacc  = (float*)alloc(256);
    int*   cnt   = (int*)alloc(65536);

    hipMemsetAsync(raw,  0, 64 * 1024 * 2, stream);   // h0 = 0 (raw[0])
    hipMemsetAsync(dist, 0, 10 * 8192 * 4, stream);
    hipMemsetAsync(lacc, 0, 256, stream);
    hipMemsetAsync(cnt,  0, 65536, stream);           // per-(step,group) barrier counters

    conv_kernel<<<2048, 256, 0, stream>>>(emb, emb_b, 32000 * 1024);
    conv_kernel<<<512, 256, 0, stream>>>(Wih, Wih_b, 1024 * 1024);
    conv_kernel<<<512, 256, 0, stream>>>(Whh, Whh_b, 1024 * 1024);

    // Phase A: XWb = emb[data] @ Wih^T + bih  (bf16)
    gemm_kernel<0><<<512, 256, 0, stream>>>(data, emb_b, Wih_b, bih,
                                            nullptr, nullptr, XWb, nullptr);
    // Phase B: all 128 RNN steps, point-coherent h exchange
    rnn_fused<<<256, 128, 0, stream>>>(raw, Whh_b, XWb, bih, bhh, Ust, cnt);

    // pos term
    pos_kernel<<<512, 256, 0, stream>>>(raw, lacc);

    // Phase D: sampled negatives GEMM + fused dist epilogue (s flattened: 5120 blocks)
    gemm_kernel<1><<<5120, 256, 0, stream>>>(samples, emb_b, Wih_b, bih,
                                             Ust, raw, nullptr, dist);

    finalize_kernel<<<1, 1024, 0, stream>>>(dist, lacc, (float*)d_out);
}

// Round 6
// 873.218 us; speedup vs baseline: 2.8768x; 1.5594x over previous
//
#include <hip/hip_runtime.h>
#include <hip/hip_bf16.h>
#include <cmath>

typedef __bf16 bf16;
typedef __attribute__((ext_vector_type(8))) __bf16 bf16x8;
typedef __attribute__((ext_vector_type(4))) __bf16 bf16x4;
typedef __attribute__((ext_vector_type(4))) float f32x4;
typedef unsigned long long ull;

#define TEMPC 65.0f
#define EPSC 1e-6f

#define GLD_LDS16(gptr, lptr)                                                             \
    __builtin_amdgcn_global_load_lds(                                                     \
        (const __attribute__((address_space(1))) unsigned int*)(gptr),                    \
        (__attribute__((address_space(3))) unsigned int*)(lptr), 16, 0, 0)

// ---------------- f32 -> bf16 convert ----------------
__global__ void conv_kernel(const float* __restrict__ s, bf16* __restrict__ d, int n)
{
    int i = (blockIdx.x * blockDim.x + threadIdx.x) * 4;
    const int stride = gridDim.x * blockDim.x * 4;
    for (; i < n; i += stride) {
        const float4 v = *(const float4*)(s + i);
        bf16x4 o;
        o[0] = (bf16)v.x; o[1] = (bf16)v.y; o[2] = (bf16)v.z; o[3] = (bf16)v.w;
        *(bf16x4*)(d + i) = o;
    }
}

// ---------------- depth-2 pipelined MFMA GEMM: gathered-A [128 rows] @ W^T ----------------
// 128x128 C-tile, BK=32, double-buffered LDS, counted vmcnt(4) (2 K-steps in flight),
// LDS read-conflict fix via pre-swizzled global source (kc ^= (row>>1)&3).
template<int MODE>
__global__ __launch_bounds__(256)
void gemm_kernel(const int* __restrict__ idx, const bf16* __restrict__ emb,
                 const bf16* __restrict__ Wmat, const float* __restrict__ bih,
                 const bf16* __restrict__ Ust, const bf16* __restrict__ prevb,
                 bf16* __restrict__ XWout, float* __restrict__ dist)
{
    __shared__ __align__(16) bf16 As[2 * 128 * 32];   // 2 bufs x 8KB
    __shared__ __align__(16) bf16 Bs[2 * 128 * 32];

    const int tid = threadIdx.x;
    const int l  = tid & 63;
    const int w  = tid >> 6;
    const int wr = w >> 1, wc = w & 1;                // wave quadrant (64x64)

    int s, within;
    if (MODE == 0) {
        const int wg = (blockIdx.x & 7) * 64 + (blockIdx.x >> 3);   // XCD swizzle (512%8==0)
        s = 0; within = wg;
    } else {
        const int wg = (blockIdx.x & 7) * 640 + (blockIdx.x >> 3);  // XCD swizzle (5120%8==0)
        s = wg >> 9; within = wg & 511;
    }
    const int mbase = (within >> 3) * 128;
    const int nbase = (within & 7) * 128;

    const int r0 = w * 32 + (l >> 2);                 // rows r0, r0+16
    const int csw = ((l & 3) ^ ((l >> 3) & 3)) * 16;  // swizzled 16B sub-chunk
    const char* Bsrc0 = (const char*)Wmat + (size_t)(nbase + r0) * 2048 + csw;
    const char* Bsrc1 = (const char*)Wmat + (size_t)(nbase + r0 + 16) * 2048 + csw;
    const char* Asrc0 = (const char*)emb + (size_t)idx[s * 8192 + mbase + r0] * 2048 + csw;
    const char* Asrc1 = (const char*)emb + (size_t)idx[s * 8192 + mbase + r0 + 16] * 2048 + csw;

    const int frow  = l & 15;
    const int koffE = (((l >> 4) ^ ((frow >> 1) & 3)) * 8);   // element offset in 32-el row
    const bf16* Ard = As + (wr * 64 + frow) * 32 + koffE;
    const bf16* Brd = Bs + (wc * 64 + frow) * 32 + koffE;

    auto stage = [&](int buf, int kb) {
        bf16* As_ = As + buf * 4096 + w * 1024;       // wave-uniform dest (+lane*16 implicit)
        bf16* Bs_ = Bs + buf * 4096 + w * 1024;
        GLD_LDS16(Asrc0 + kb, As_);
        GLD_LDS16(Asrc1 + kb, As_ + 512);
        GLD_LDS16(Bsrc0 + kb, Bs_);
        GLD_LDS16(Bsrc1 + kb, Bs_ + 512);
    };

    stage(0, 0);
    stage(1, 64);

    f32x4 acc[4][4] = {};
    for (int k = 0; k < 32; ++k) {
        if (k == 31) asm volatile("s_waitcnt vmcnt(0)" ::: "memory");
        else         asm volatile("s_waitcnt vmcnt(4)" ::: "memory");  // buf k ready, k+1 flying
        __syncthreads();
        const bf16* Ab = Ard + (k & 1) * 4096;
        const bf16* Bb = Brd + (k & 1) * 4096;
        bf16x8 af[4], bfr[4];
        #pragma unroll
        for (int mt = 0; mt < 4; ++mt) af[mt]  = *(const bf16x8*)(Ab + mt * 16 * 32);
        #pragma unroll
        for (int nt = 0; nt < 4; ++nt) bfr[nt] = *(const bf16x8*)(Bb + nt * 16 * 32);
        #pragma unroll
        for (int mt = 0; mt < 4; ++mt)
            #pragma unroll
            for (int nt = 0; nt < 4; ++nt)
                acc[mt][nt] = __builtin_amdgcn_mfma_f32_16x16x32_bf16(af[mt], bfr[nt], acc[mt][nt], 0, 0, 0);
        __syncthreads();                                  // all waves done reading buf k
        if (k + 2 < 32) stage(k & 1, (k + 2) * 64);       // refill buf k with step k+2
    }

    if (MODE == 0) {
        #pragma unroll
        for (int mt = 0; mt < 4; ++mt)
            #pragma unroll
            for (int nt = 0; nt < 4; ++nt) {
                const int colg = nbase + wc * 64 + nt * 16 + frow;
                const float bi = bih[colg];
                #pragma unroll
                for (int r = 0; r < 4; ++r) {
                    const int rowg = mbase + wr * 64 + mt * 16 + (l >> 4) * 4 + r;
                    XWout[(size_t)rowg * 1024 + colg] = (bf16)(acc[mt][nt][r] + bi);
                }
            }
    } else {
        #pragma unroll
        for (int mt = 0; mt < 4; ++mt)
            #pragma unroll
            for (int r = 0; r < 4; ++r) {
                const int rowg = mbase + wr * 64 + mt * 16 + (l >> 4) * 4 + r;
                float p = 0.f;
                #pragma unroll
                for (int nt = 0; nt < 4; ++nt) {
                    const int colg = nbase + wc * 64 + nt * 16 + frow;
                    const size_t e = (size_t)rowg * 1024 + colg;
                    const float o = tanhf(acc[mt][nt][r] + (float)Ust[e]);
                    const float d = (float)prevb[e] - o + EPSC;
                    p += d * d;
                }
                #pragma unroll
                for (int off = 1; off < 16; off <<= 1)
                    p += __shfl_xor(p, off, 16);
                if (frow == 0) atomicAdd(&dist[s * 8192 + rowg], p);
            }
    }
}

// ---------------- fused 128-step RNN: cooperative LDS h-staging, relaxed signaling ------
// 256 blocks x 128 thr (1/CU). Block (group=bid&7, slot=bid>>3): batch rows
// [group*8,group*8+8), j-cols [slot*32,+32). Whh slice LDS-resident (64KB, swizzled).
// Per step: poll -> 16x8B coherent loads of group h (16KB, cooperative, ONE latency
// window) -> LDS -> 32 MFMA (2 acc chains) -> tanh -> coherent packed h stores ->
// syncthreads (acks drained) -> RELAXED signal add (no wbl2: h is write-through).
__global__ __launch_bounds__(128, 1)
void rnn_fused(bf16* __restrict__ raw, const bf16* __restrict__ Whh,
               const bf16* __restrict__ XWb, const float* __restrict__ bih,
               const float* __restrict__ bhh, bf16* __restrict__ Ust,
               int* __restrict__ cnt)
{
    __shared__ __align__(16) bf16 Wlds[32 * 1024];       // 64KB Whh slice (swizzled)
    __shared__ __align__(16) char Hlds[8 * 2064];        // h_t: 8 rows, stride 2064B (pad)

    const int tid    = threadIdx.x;
    const int l      = tid & 63;
    const int w      = tid >> 6;            // wave = j-tile (0,1)
    const int group  = blockIdx.x & 7;      // batch group
    const int slot   = blockIdx.x >> 3;     // j-slice within group
    const int jbase  = slot * 32;
    const int frow   = l & 15;
    const int kchunk = l >> 4;
    const int jglob  = jbase + w * 16 + frow;
    const int rr     = frow & 7;            // real h row (8 rows duplicated to 16)

    // Stage Whh j-slice into LDS once, source pre-swizzled (kc ^= (j>>1)&3)
    {
        const int jloc = l >> 2;
        const int csw  = ((l & 3) ^ ((l >> 3) & 3)) * 16;
        const char* gsrc = (const char*)Whh + (size_t)(jbase + w * 16 + jloc) * 2048 + csw;
        for (int kk = 0; kk < 32; ++kk)
            GLD_LDS16(gsrc + kk * 64, Wlds + (kk * 2 + w) * 512);
        asm volatile("s_waitcnt vmcnt(0)" ::: "memory");
        __syncthreads();
    }
    const float bh = bhh[jglob];
    const float bi = bih[jglob];

    // swizzled Wlds fragment read base; +kk*1024 elements per k-block
    const int ksw   = kchunk ^ ((frow >> 1) & 3);
    const bf16* wrd = Wlds + w * 512 + frow * 32 + ksw * 8;
    // Hlds fragment read base; +kk*64 bytes per k-block
    const char* hrd = Hlds + rr * 2064 + kchunk * 16;

    for (int t = 0; t < 128; ++t) {
        if (t > 0) {
            if (tid == 0)
                while (__hip_atomic_load(&cnt[(t * 8 + group) * 16], __ATOMIC_RELAXED,
                                         __HIP_MEMORY_SCOPE_AGENT) < 32)
                    __builtin_amdgcn_s_sleep(1);
            __syncthreads();
        }
        // cooperative coherent fetch of group h_t (16KB): 128 thr x 16 x 8B, one window
        const ull* hsrc8 = (const ull*)(raw + (size_t)t * 65536 + group * 8192);
        ull hv[16];
        #pragma unroll
        for (int i = 0; i < 16; ++i)
            hv[i] = __hip_atomic_load(hsrc8 + tid + i * 128,
                                      __ATOMIC_RELAXED, __HIP_MEMORY_SCOPE_AGENT);
        // XWb for this step (cached path, latency hidden under h window)
        float xw[4];
        #pragma unroll
        for (int r = 0; r < 4; ++r) {
            const int bc = ((l >> 4) * 4 + r) & 7;
            xw[r] = (float)XWb[(size_t)(t * 64 + group * 8 + bc) * 1024 + jglob];
        }
        #pragma unroll
        for (int i = 0; i < 16; ++i) {
            const int c = tid + i * 128;                 // 256 8B-chunks per row
            *(ull*)(Hlds + (c >> 8) * 2064 + (c & 255) * 8) = hv[i];
        }
        __syncthreads();

        f32x4 acc0 = {0.f,0.f,0.f,0.f}, acc1 = {0.f,0.f,0.f,0.f};
        #pragma unroll
        for (int kk = 0; kk < 32; kk += 2) {
            bf16x8 a0 = *(const bf16x8*)(hrd + kk * 64);
            bf16x8 a1 = *(const bf16x8*)(hrd + kk * 64 + 64);
            acc0 = __builtin_amdgcn_mfma_f32_16x16x32_bf16(a0, *(const bf16x8*)(wrd + kk * 1024),       acc0, 0, 0, 0);
            acc1 = __builtin_amdgcn_mfma_f32_16x16x32_bf16(a1, *(const bf16x8*)(wrd + (kk + 1) * 1024), acc1, 0, 0, 0);
        }

        bf16* rawN = raw + (size_t)(t + 1) * 65536;
        if (l < 32) {                               // rows 0-7 real
            #pragma unroll
            for (int r = 0; r < 4; ++r) {
                const int b = (l >> 4) * 4 + r;
                const float V = acc0[r] + acc1[r] + bh;             // h @ Whh^T + b_hh
                const float h = tanhf(xw[r] + V);
                const size_t row = (size_t)(t * 64 + group * 8 + b);
                Ust[row * 1024 + jglob] = (bf16)(V + bi);           // normal store (later kernel)
                const bf16 hb = (bf16)h;
                unsigned short hs = __builtin_bit_cast(unsigned short, hb);
                unsigned short hn = (unsigned short)__shfl_down((int)hs, 1, 64);
                if ((frow & 1) == 0) {                              // pack 2 cols -> 4B store
                    unsigned int pack = (unsigned int)hs | ((unsigned int)hn << 16);
                    unsigned int* dst = (unsigned int*)(rawN + (size_t)(group * 8 + b) * 1024 + jglob);
                    __hip_atomic_store(dst, pack, __ATOMIC_RELAXED, __HIP_MEMORY_SCOPE_AGENT);
                }
            }
        }
        if (t < 127) {
            __syncthreads();                        // all waves' store acks drained here
            if (tid == 0)                           // relaxed: write-through stores already
                __hip_atomic_fetch_add(&cnt[((t + 1) * 8 + group) * 16], 1,   // at coherent pt
                                       __ATOMIC_RELAXED, __HIP_MEMORY_SCOPE_AGENT);
        }
    }
}

// ---------------- pos term: (65/128) * sum (raw[t]-raw[t+1]+eps)^2 ----------------
__global__ void pos_kernel(const bf16* __restrict__ raw, float* __restrict__ lacc)
{
    float s = 0.f;
    const int NV = (128 * 64 * 1024) / 8;
    for (int i = blockIdx.x * blockDim.x + threadIdx.x; i < NV; i += gridDim.x * blockDim.x) {
        bf16x8 a = *(const bf16x8*)(raw + (size_t)i * 8);
        bf16x8 b = *(const bf16x8*)(raw + (size_t)i * 8 + 65536);
        #pragma unroll
        for (int j = 0; j < 8; ++j) {
            const float d = (float)a[j] - (float)b[j] + EPSC;
            s += d * d;
        }
    }
    #pragma unroll
    for (int off = 32; off > 0; off >>= 1) s += __shfl_down(s, off, 64);
    if ((threadIdx.x & 63) == 0) atomicAdd(lacc, s * (TEMPC / 128.f));
}

// ---------------- finalize: clip, exp, log, total ----------------
__global__ __launch_bounds__(1024)
void finalize_kernel(const float* __restrict__ dist, const float* __restrict__ lacc,
                     float* __restrict__ out)
{
    float s = 0.f;
    for (int r = threadIdx.x; r < 8192; r += 1024) {
        float se = 0.f;
        #pragma unroll
        for (int k = 0; k < 10; ++k) {
            float dd = dist[k * 8192 + r];
            dd = fminf(fmaxf(dd, 0.f), 0.01f);
            se += expf(-dd);
        }
        s += logf(se * (1.f / 8192.f) + EPSC);
    }
    #pragma unroll
    for (int off = 32; off > 0; off >>= 1) s += __shfl_down(s, off, 64);
    __shared__ float red[16];
    const int wave = threadIdx.x >> 6;
    if ((threadIdx.x & 63) == 0) red[wave] = s;
    __syncthreads();
    if (threadIdx.x == 0) {
        float tot = 0.f;
        #pragma unroll
        for (int i = 0; i < 16; ++i) tot += red[i];
        out[0] = tot + lacc[0];
    }
}

extern "C" void kernel_launch(void* const* d_in, const int* in_sizes, int n_in,
                              void* d_out, int out_size, void* d_ws, size_t ws_size,
                              hipStream_t stream)
{
    const int*   data    = (const int*)d_in[0];   // [128*64]
    const int*   samples = (const int*)d_in[1];   // [10*8192]
    const float* emb     = (const float*)d_in[2]; // [32000*1024]
    const float* Wih     = (const float*)d_in[3]; // [1024*1024]
    const float* bih     = (const float*)d_in[4]; // [1024]
    const float* Whh     = (const float*)d_in[5]; // [1024*1024]
    const float* bhh     = (const float*)d_in[6]; // [1024]

    char* ws = (char*)d_ws;
    size_t off = 0;
    auto alloc = [&](size_t bytes) { void* p = ws + off; off += (bytes + 255) & ~(size_t)255; return p; };
    bf16*  emb_b = (bf16*)alloc((size_t)32000 * 1024 * 2);
    bf16*  Wih_b = (bf16*)alloc((size_t)1024 * 1024 * 2);
    bf16*  Whh_b = (bf16*)alloc((size_t)1024 * 1024 * 2);
    bf16*  XWb   = (bf16*)alloc((size_t)8192 * 1024 * 2);
    bf16*  Ust   = (bf16*)alloc((size_t)8192 * 1024 * 2);
    bf16*  raw   = (bf16*)alloc((size_t)129 * 64 * 1024 * 2);
    float* dist  = (float*)alloc((size_t)10 * 8192 * 4);
    float* lacc  = (float*)alloc(256);
    int*   cnt   = (int*)alloc(65536);

    hipMemsetAsync(raw,  0, 64 * 1024 * 2, stream);   // h0 = 0 (raw[0])
    hipMemsetAsync(dist, 0, 10 * 8192 * 4, stream);
    hipMemsetAsync(lacc, 0, 256, stream);
    hipMemsetAsync(cnt,  0, 65536, stream);           // per-(step,group) barrier counters

    conv_kernel<<<2048, 256, 0, stream>>>(emb, emb_b, 32000 * 1024);
    conv_kernel<<<512, 256, 0, stream>>>(Wih, Wih_b, 1024 * 1024);
    conv_kernel<<<512, 256, 0, stream>>>(Whh, Whh_b, 1024 * 1024);

    // Phase A: XWb = emb[data] @ Wih^T + bih  (bf16)
    gemm_kernel<0><<<512, 256, 0, stream>>>(data, emb_b, Wih_b, bih,
                                            nullptr, nullptr, XWb, nullptr);
    // Phase B: all 128 RNN steps, cooperative coherent h exchange
    rnn_fused<<<256, 128, 0, stream>>>(raw, Whh_b, XWb, bih, bhh, Ust, cnt);

    // pos term
    pos_kernel<<<512, 256, 0, stream>>>(raw, lacc);

    // Phase D: sampled negatives GEMM + fused dist epilogue (s flattened: 5120 blocks)
    gemm_kernel<1><<<5120, 256, 0, stream>>>(samples, emb_b, Wih_b, bih,
                                             Ust, raw, nullptr, dist);

    finalize_kernel<<<1, 1024, 0, stream>>>(dist, lacc, (float*)d_out);
}